// Round 7
// baseline (282.749 us; speedup 1.0000x reference)
//
#include <hip/hip_runtime.h>

// SoftDTW: B=16, T=1024, C=64, gamma=0.01, BIG=1e10
// out = sum_b softdtw(cost[b]) ; cost[b][i][j] = ||x[b,i]-y[b,j]||^2
//
// R7: decoupled systolic DP with FENCELESS message-passing handoff.
// R6 post-mortem: 11.5K cyc/window sustained, ~95% stall in flag RTT +
// acquire fence + boundary load, all serial per window. Fix: boundary
// values are write-once tagged u64 messages (tag<<32 | f32) stored with
// relaxed agent-scope 8B atomics; consumer prefetches next window's 64
// pairs (1/lane) during current window compute -> steady-state handoff
// cost ~= one tag compare. No fences, no flags, no ack (write-once).
// 256 blocks x 64 threads, 1 wave/CU; bid swizzle (b=bid&15,p=bid>>4)
// keeps a batch's 16 bands on one XCD (bid%8=XCD) - perf only.

#define TT 1024
#define BB 16
#define CC 64
#define BIGV 1e10f
#define NW 16
#define NCH 16
#define NROWS (NW * TT)          // 16384 skew rows per batch (merged packing)
#define NPAIR 15                 // band pairs per batch

// ---------------------------------------------------------------------------
// Kernel 1: cost tile 64x64 -> skewed coalesced store via LDS shear.
// cost = xn + yn + sum(-2x*y). (R6 version; k-loop fully unrolled)
// ---------------------------------------------------------------------------
__global__ __launch_bounds__(256) void skew_cost_kernel(const float* __restrict__ x,
                                                        const float* __restrict__ y,
                                                        float* __restrict__ skew) {
    __shared__ __align__(16) float lds[2 * 64 * 68];
    __shared__ float xn[64], yn[64];
    float* xs = lds;                 // [64][68], pre-scaled by -2
    float* ys = lds + 64 * 68;       // [64][68]
    const int bx = blockIdx.x;
    const int by = blockIdx.y;
    const int bz = blockIdx.z;
    const int tid = threadIdx.x;

    const float4* xg = (const float4*)(x + ((size_t)bz * TT + by * 64) * CC);
    const float4* yg = (const float4*)(y + ((size_t)bz * TT + bx * 64) * CC);
#pragma unroll
    for (int t = 0; t < 4; ++t) {
        int idx = t * 256 + tid;
        int r = idx >> 4, f = idx & 15;
        float4 v = xg[r * 16 + f];
        xs[r * 68 + f * 4 + 0] = -2.0f * v.x; xs[r * 68 + f * 4 + 1] = -2.0f * v.y;
        xs[r * 68 + f * 4 + 2] = -2.0f * v.z; xs[r * 68 + f * 4 + 3] = -2.0f * v.w;
        float4 u = yg[r * 16 + f];
        ys[r * 68 + f * 4 + 0] = u.x; ys[r * 68 + f * 4 + 1] = u.y;
        ys[r * 68 + f * 4 + 2] = u.z; ys[r * 68 + f * 4 + 3] = u.w;
    }
    __syncthreads();

    if (tid < 128) {
        int r = tid & 63;
        const float* row = (tid < 64) ? (xs + r * 68) : (ys + r * 68);
        float s = 0.f;
#pragma unroll
        for (int k4 = 0; k4 < 16; ++k4) {
            float4 v = *(const float4*)&row[4 * k4];
            s = fmaf(v.x, v.x, s); s = fmaf(v.y, v.y, s);
            s = fmaf(v.z, v.z, s); s = fmaf(v.w, v.w, s);
        }
        if (tid < 64) xn[r] = 0.25f * s; else yn[r] = s;
    }

    const int tr = tid >> 4, tc = tid & 15;
    float acc[4][4] = {};
#pragma unroll
    for (int k4 = 0; k4 < 16; ++k4) {
        float4 xa4[4], yb4[4];
#pragma unroll
        for (int a = 0; a < 4; ++a) xa4[a] = *(const float4*)&xs[(4 * tr + a) * 68 + 4 * k4];
#pragma unroll
        for (int b = 0; b < 4; ++b) yb4[b] = *(const float4*)&ys[(4 * tc + b) * 68 + 4 * k4];
#pragma unroll
        for (int a = 0; a < 4; ++a)
#pragma unroll
            for (int b = 0; b < 4; ++b) {
                acc[a][b] = fmaf(xa4[a].x, yb4[b].x, acc[a][b]);
                acc[a][b] = fmaf(xa4[a].y, yb4[b].y, acc[a][b]);
                acc[a][b] = fmaf(xa4[a].z, yb4[b].z, acc[a][b]);
                acc[a][b] = fmaf(xa4[a].w, yb4[b].w, acc[a][b]);
            }
    }
    __syncthreads();

    float xnr[4], ynr[4];
#pragma unroll
    for (int a = 0; a < 4; ++a) { xnr[a] = xn[4 * tr + a]; ynr[a] = yn[4 * tc + a]; }

    float* sh = lds;                 // sh[d][l], d = jl + l, stride 68
#pragma unroll
    for (int a = 0; a < 4; ++a)
#pragma unroll
        for (int b = 0; b < 4; ++b) {
            int l = 4 * tr + a, jl = 4 * tc + b;
            sh[(l + jl) * 68 + l] = acc[a][b] + xnr[a] + ynr[b];
        }
    __syncthreads();

    const int l = tid & 63, wv = tid >> 6;
    float* sb = skew + (size_t)bz * NROWS * 64;
    const int r0 = by * TT + bx * 64;
    for (int d = wv; d < 127; d += 4) {
        float v = sh[d * 68 + l];
        int lo = d - 63; lo = lo < 0 ? 0 : lo;
        int hi = d < 63 ? d : 63;
        int row = r0 + d; if (row >= NROWS) row -= NROWS;
        if (l >= lo && l <= hi) sb[(size_t)row * 64 + l] = v;
    }
}

// lane l gets lane l-1's `cur`; lane 0 gets `lane0val` (via dpp old operand).
__device__ __forceinline__ float shift_up1(float cur, float lane0val) {
    int r = __builtin_amdgcn_update_dpp(__float_as_int(lane0val),
                                        __float_as_int(cur),
                                        0x138 /*WAVE_SHR1*/, 0xF, 0xF, false);
    return __int_as_float(r);
}

// 32 DP steps. PHASE: 0=fill(k 0..31/32..63 with l<=k mask), 1=mid(all
// active), 2=drain k 0..31 (l>=k+1), 3=drain k 32..62 (l>=k+1, skip k=63).
template<int PHASE, int KOFS>
__device__ __forceinline__ void run32(float& cur, float& diag,
                                      const float (&q)[64],
                                      const float* cb, float* pA, float* pB,
                                      int l) {
#pragma unroll
    for (int g = 0; g < 8; ++g) {
        float4 b4;
        if (PHASE <= 1) b4 = *(const float4*)(cb + KOFS + 4 * g);
        else            b4 = make_float4(BIGV, BIGV, BIGV, BIGV);
        const float* bv = (const float*)&b4;
#pragma unroll
        for (int kk = 0; kk < 4; ++kk) {
            const int k = KOFS + 4 * g + kk;
            if (!(PHASE == 3 && k == 63)) {
                float up = shift_up1(cur, bv[kk]);        // R[i-1][j]
                float mn = fminf(fminf(up, cur), diag);   // v_min3
                float nv = q[k] + mn;
                if (PHASE == 0)      cur = (l <= k) ? nv : cur;
                else if (PHASE >= 2) cur = (l >= k + 1) ? nv : cur;
                else                 cur = nv;
                diag = up;                                // SSA rename
                if (k < 63) pA[k + 1] = cur;              // ring/dump, imm ofs
                else        pB[0] = cur;
            }
        }
    }
}

// ---------------------------------------------------------------------------
// Kernel 2: systolic DP, 1 wave per (batch, band). 17 windows of 64 cols.
// ---------------------------------------------------------------------------
__global__ __launch_bounds__(64) void dtw_sys(const float* __restrict__ skew,
                                              unsigned long long* __restrict__ bndmsg,
                                              float* __restrict__ out) {
    __shared__ float pubring[128];     // lane63 boundary staging, slot=cb&127
    __shared__ float dumpL[192];       // sink for lanes 0..62
    __shared__ float bndbuf[64];       // incoming boundary, current window
    const int bid = blockIdx.x;
    const int b = bid & 15;            // batch (bid%8 = XCD -> batch-local)
    const int p = bid >> 4;            // band
    const int l = threadIdx.x;

    const float* Dbat = skew + (size_t)b * NROWS * 64 + l;
    unsigned long long* BndOut = bndmsg + ((size_t)b * NPAIR + p) * TT;
    unsigned long long* BndIn  = bndmsg + ((size_t)b * NPAIR + (p > 0 ? p - 1 : 0)) * TT;

    bndbuf[l] = BIGV;                  // stays BIG for p==0 / drain

    float cur = BIGV;                                  // R[i][j-1] carried
    float diag = (p == 0 && l == 0) ? 0.0f : BIGV;     // R[i-1][j-1] carried

    float qA[64], qB[64];
    auto loadw = [&](int Vn, float (&q)[64]) {         // cost rows, window Vn
        const int r0 = (p * TT + 64 * Vn) & (NROWS - 1);  // 64-aligned wrap
        const float* g0 = Dbat + (size_t)r0 * 64;
#pragma unroll
        for (int h = 0; h < 4; ++h) {
            const float* gp = g0 + (size_t)h * 16 * 64;
#pragma unroll
            for (int k = 0; k < 16; ++k) q[16 * h + k] = gp[(size_t)k * 64];
        }
    };
    loadw(0, qA);
    loadw(1, qB);

    unsigned long long mcur = 0, mnext = 0;
    if (p > 0)
        mcur = __hip_atomic_load(&BndIn[l], __ATOMIC_RELAXED,
                                 __HIP_MEMORY_SCOPE_AGENT);

    auto window = [&](int V, float (&q)[64]) {
        // consume: tag-checked prefetched messages -> bndbuf
        if (p > 0 && V <= 15) {
            const unsigned want = (unsigned)(V + 1);
            while (!__all((int)((unsigned)(mcur >> 32) == want))) {
                __builtin_amdgcn_s_sleep(1);
                mcur = __hip_atomic_load(&BndIn[(size_t)64 * V + l],
                                         __ATOMIC_RELAXED,
                                         __HIP_MEMORY_SCOPE_AGENT);
            }
            bndbuf[l] = __uint_as_float((unsigned)mcur);
            if (V < 15)
                mnext = __hip_atomic_load(&BndIn[(size_t)64 * (V + 1) + l],
                                          __ATOMIC_RELAXED,
                                          __HIP_MEMORY_SCOPE_AGENT);
        }
        const bool is_pub = (l == 63);
        float* pA = (is_pub && V > 0) ? (pubring + (((V + 1) & 1) << 6))
                                      : (dumpL + l);
        float* pB = (is_pub && V < 16) ? (pubring + ((V & 1) << 6))
                                       : (dumpL + l);
        if (V == 0) {
            run32<0, 0>(cur, diag, q, bndbuf, pA, pB, l);
            run32<0, 32>(cur, diag, q, bndbuf, pA, pB, l);
        } else if (V < 16) {
            run32<1, 0>(cur, diag, q, bndbuf, pA, pB, l);
            run32<1, 32>(cur, diag, q, bndbuf, pA, pB, l);
        } else {
            run32<2, 0>(cur, diag, q, bndbuf, pA, pB, l);
            run32<3, 32>(cur, diag, q, bndbuf, pA, pB, l);
        }
        // flush boundary window V-1 (completed by window V's steps)
        if (V >= 1 && p < NPAIR) {
            float fv = pubring[(((V + 1) & 1) << 6) + l];
            unsigned long long msg =
                ((unsigned long long)(unsigned)V << 32) | __float_as_uint(fv);
            __hip_atomic_store(&BndOut[(size_t)64 * (V - 1) + l], msg,
                               __ATOMIC_RELAXED, __HIP_MEMORY_SCOPE_AGENT);
        }
        mcur = mnext;
    };

#pragma unroll 1
    for (int h = 0; h < 8; ++h) {
        window(2 * h, qA);
        loadw(2 * h + 2, qA);                 // h=7 -> loadw(16): drain rows
        window(2 * h + 1, qB);
        if (h < 7) loadw(2 * h + 3, qB);
    }
    window(16, qA);                           // drain: steps 1024..1086

    // band 15, lane 63 holds R[1024][1024]
    if (p == NPAIR && l == 63) atomicAdd(out, cur);
}

// ---------------------------------------------------------------------------
// Mid fallback (ws fits skew only): R5 barrier-tile DP (verified at 133us).
// ---------------------------------------------------------------------------
#define BROW 1024
#define BND_DUMMY_OFF (16 * BROW)
#define DUMP_OFF (17 * BROW)
#define BND_SIZE (17 * BROW + 256)

__global__ __launch_bounds__(1024, 4) void dtw_kernel(const float* __restrict__ skew,
                                                      float* __restrict__ out) {
    __shared__ float bnd[BND_SIZE];
    const int tid = threadIdx.x;
    const int l = tid & 63;
    const int w = __builtin_amdgcn_readfirstlane(tid >> 6);

    bnd[BND_DUMMY_OFF + tid] = BIGV;
    __syncthreads();

    const float* Dbat = skew + (size_t)blockIdx.x * NROWS * 64;
    const int bro = ((w == 0) ? 16 : (w - 1)) * BROW;
    const bool is_pub = (l == 63) && (w < NW - 1);
    const int Rw = w * TT;

    float cur = BIGV, diag = BIGV;

#pragma unroll 1
    for (int m = 0; m < 31; ++m) {
        const int c = m - w;
        if (c >= 0 && c < 16) {
            const int base = c * 64;
            float i0v = (base == 0) ? ((w == 0) ? 0.0f : BIGV)
                                    : bnd[bro + (base - 1)];
            diag = (l == 0) ? i0v : diag;
            float* pub = bnd + (is_pub ? (w * BROW - 63 + base) : (DUMP_OFF + l - 63));
            const int R0 = Rw + base;
            float cq[3][16];
            float4 bq[2][4];
            auto loadc = [&](int g, float (&q)[16]) {
                int r0 = R0 + 16 * g;
                if (r0 >= NROWS) r0 -= NROWS;
                const float* gb = Dbat + (size_t)r0 * 64;
#pragma unroll
                for (int k = 0; k < 16; ++k) q[k] = gb[l + 64 * k];
            };
            auto loadb = [&](int g, float4 (&bb)[4]) {
                const float4* bp = (const float4*)(bnd + bro + base + 16 * g);
#pragma unroll
                for (int k = 0; k < 4; ++k) bb[k] = bp[k];
            };
            loadc(0, cq[0]); loadc(1, cq[1]);
            loadb(0, bq[0]);
#pragma unroll
            for (int g = 0; g < 8; ++g) {
                if (g + 2 < 8) loadc(g + 2, cq[(g + 2) % 3]);
                if (g + 1 < 8) loadb(g + 1, bq[(g + 1) & 1]);
                const float* q = cq[g % 3];
                const float* bv = (const float*)bq[g & 1];
#pragma unroll
                for (int k = 0; k < 16; ++k) {
                    const int s = 16 * g + k;
                    float up = shift_up1(cur, bv[k]);
                    float mn = fminf(fminf(up, cur), diag);
                    float nv = q[k] + mn;
                    bool act = (s < 64) ? (l <= s) : (l >= s - 63);
                    cur = act ? nv : cur;
                    diag = up;
                    if (s >= 63) pub[s] = cur;
                }
            }
        }
        __syncthreads();
    }
    if (tid == 1023) atomicAdd(out, cur);
}

// ---------------------------------------------------------------------------
// Last-resort fallback: naive fused DP.
// ---------------------------------------------------------------------------
__device__ __forceinline__ float softmin3(float a, float b, float c) {
    float m = fminf(fminf(a, b), c);
    float s = expf((m - a) * 100.0f) + expf((m - b) * 100.0f) + expf((m - c) * 100.0f);
    return m - 0.01f * logf(s);
}

__global__ __launch_bounds__(1024) void dtw_fly_kernel(const float* __restrict__ x,
                                                       const float* __restrict__ y,
                                                       float* __restrict__ out) {
    __shared__ float rbuf[3][TT + 1];
    const int b = blockIdx.x;
    const int t = threadIdx.x;

    float4 xr[16];
    const float4* xrow = (const float4*)(x + ((size_t)b * TT + t) * CC);
#pragma unroll
    for (int q = 0; q < 16; ++q) xr[q] = xrow[q];

    rbuf[0][t] = (t == 0) ? 0.0f : BIGV;
    rbuf[1][t] = BIGV;
    if (t == 0) { rbuf[0][TT] = BIGV; rbuf[1][TT] = BIGV; }
    __syncthreads();

    int p2 = 0, p1 = 1, pc = 2;
    float val = BIGV;
    for (int d = 2; d <= 2 * TT; ++d) {
        int j = d - t - 1;
        bool valid = (j >= 1) && (j <= TT);
        float cv = 0.0f;
        if (valid) {
            const float4* yr = (const float4*)(y + ((size_t)b * TT + (j - 1)) * CC);
#pragma unroll
            for (int q = 0; q < 16; ++q) {
                float4 yv = yr[q];
                float d0 = xr[q].x - yv.x, d1 = xr[q].y - yv.y;
                float d2 = xr[q].z - yv.z, d3 = xr[q].w - yv.w;
                cv += d0 * d0 + d1 * d1 + d2 * d2 + d3 * d3;
            }
        }
        float v = cv + softmin3(rbuf[p1][t], rbuf[p1][t + 1], rbuf[p2][t]);
        val = valid ? v : BIGV;
        rbuf[pc][t + 1] = val;
        if (t == 0) rbuf[pc][0] = BIGV;
        __syncthreads();
        int tmp = p2; p2 = p1; p1 = pc; pc = tmp;
    }
    if (t == TT - 1) atomicAdd(out, val);
}

extern "C" void kernel_launch(void* const* d_in, const int* in_sizes, int n_in,
                              void* d_out, int out_size, void* d_ws, size_t ws_size,
                              hipStream_t stream) {
    const float* x = (const float*)d_in[0];
    const float* y = (const float*)d_in[1];
    float* out = (float*)d_out;

    hipMemsetAsync(d_out, 0, sizeof(float) * out_size, stream);

    const size_t skew_b = (size_t)BB * NROWS * 64 * sizeof(float);          // 64 MiB
    const size_t msg_b  = (size_t)BB * NPAIR * TT * sizeof(unsigned long long); // 1.875 MiB

    if (ws_size >= skew_b + msg_b) {
        float* skew = (float*)d_ws;
        unsigned long long* bndmsg = (unsigned long long*)((char*)d_ws + skew_b);
        hipMemsetAsync(bndmsg, 0, msg_b, stream);   // tags := 0 (invalid)
        dim3 g1(NCH, NW, BB);
        skew_cost_kernel<<<g1, 256, 0, stream>>>(x, y, skew);
        dtw_sys<<<256, 64, 0, stream>>>(skew, bndmsg, out);
    } else if (ws_size >= skew_b) {
        float* skew = (float*)d_ws;
        dim3 g1(NCH, NW, BB);
        skew_cost_kernel<<<g1, 256, 0, stream>>>(x, y, skew);
        dtw_kernel<<<BB, 1024, 0, stream>>>(skew, out);
    } else {
        dtw_fly_kernel<<<BB, 1024, 0, stream>>>(x, y, out);
    }
}